// Round 16
// baseline (686.828 us; speedup 1.0000x reference)
//
#include <hip/hip_runtime.h>

typedef __attribute__((ext_vector_type(2))) float f32x2;
typedef unsigned int uintv2 __attribute__((ext_vector_type(2)));

#define N 256
#define BLK 1024
#define NWAVE 16
#define SCALE 144.2695040888963407f  // log2(e)/0.01
#define TSTRIDE 352                  // rotated tree stride (R12-proven)
#define CTSTRIDE 36                  // transposed-C stride (R15-proven)

template <int CTRL>
__device__ __forceinline__ float dppf(float v) {
  return __int_as_float(__builtin_amdgcn_update_dpp(
      0, __float_as_int(v), CTRL, 0xF, 0xF, true));
}

#if __has_builtin(__builtin_amdgcn_permlane16_swap)
__device__ __forceinline__ float xor16_add(float x) {
  uintv2 r = __builtin_amdgcn_permlane16_swap(__float_as_uint(x),
                                              __float_as_uint(x), false, false);
  return __uint_as_float(r.x) + __uint_as_float(r.y);
}
__device__ __forceinline__ float xor16_max(float x) {
  uintv2 r = __builtin_amdgcn_permlane16_swap(__float_as_uint(x),
                                              __float_as_uint(x), false, false);
  return fmaxf(__uint_as_float(r.x), __uint_as_float(r.y));
}
#else
__device__ __forceinline__ float xor16_add(float x) {
  return x + __int_as_float(__builtin_amdgcn_ds_swizzle(__float_as_int(x), 0x401F));
}
__device__ __forceinline__ float xor16_max(float x) {
  return fmaxf(x, __int_as_float(__builtin_amdgcn_ds_swizzle(__float_as_int(x), 0x401F)));
}
#endif

#if __has_builtin(__builtin_amdgcn_permlane32_swap)
__device__ __forceinline__ float swap32_add(float a) {
  uintv2 r = __builtin_amdgcn_permlane32_swap(__float_as_uint(a),
                                              __float_as_uint(a), false, false);
  return __uint_as_float(r.x) + __uint_as_float(r.y);
}
__device__ __forceinline__ float swap32_max(float a) {
  uintv2 r = __builtin_amdgcn_permlane32_swap(__float_as_uint(a),
                                              __float_as_uint(a), false, false);
  return fmaxf(__uint_as_float(r.x), __uint_as_float(r.y));
}
#else
__device__ __forceinline__ float swap32_add(float a) { return a + __shfl_xor(a, 32); }
__device__ __forceinline__ float swap32_max(float a) { return fmaxf(a, __shfl_xor(a, 32)); }
#endif

__device__ __forceinline__ float rsum32(float v) {
  v += dppf<0x121>(v);
  v += dppf<0x122>(v);
  v += dppf<0x124>(v);
  v += dppf<0x128>(v);
  return xor16_add(v);
}
__device__ __forceinline__ float rmax32(float v) {
  v = fmaxf(v, dppf<0x121>(v));
  v = fmaxf(v, dppf<0x122>(v));
  v = fmaxf(v, dppf<0x124>(v));
  v = fmaxf(v, dppf<0x128>(v));
  return xor16_max(v);
}

// bf16 pack (RNE) / unpack-to-pair. bf16 keeps f32's exponent range
// (Round-10 lesson); trajectory accuracy proven in Round 11 (absmax 0.0039).
__device__ __forceinline__ unsigned bfpack(float lo, float hi) {
  unsigned ul = __float_as_uint(lo);
  unsigned uh = __float_as_uint(hi);
  ul = (ul + 0x7FFFu + ((ul >> 16) & 1u)) >> 16;
  uh = (uh + 0x7FFFu + ((uh >> 16) & 1u)) & 0xFFFF0000u;
  return uh | ul;
}
__device__ __forceinline__ f32x2 bf2(unsigned u) {
  f32x2 r;
  r.x = __uint_as_float(u << 16);
  r.y = __uint_as_float(u & 0xFFFF0000u);
  return r;
}

// One block = one 256x256 matrix, 16 waves. TARGET: TWO blocks per CU.
// gfx950 unified VGPR/AGPR file: every prior occupancy failure came from
// peak register pressure (f32 b = 64 regs in init) spilling to AGPR (R12:
// 60+~64=124 total -> 1 block) or scratch (R3/R13). This round caps PEAK
// live-set <= ~58: bf16-packed b (32 regs), init via 3 global re-read
// passes with per-row temps only, streaming C-pair loop. waves_per_eu(8,8)
// pins the budget at 64 both ways (min-only hint let R13 over-squeeze).
// Trajectory identical to verified R11 (bf16 b, f32 R/C/trees).
__global__ __launch_bounds__(BLK)
__attribute__((amdgpu_waves_per_eu(8, 8)))
void sinkhorn_kernel(const float* __restrict__ x, float* __restrict__ out) {
  __shared__ float ldsT[NWAVE * TSTRIDE];    // tree partials, rotated layout
  __shared__ float ldsL[N];                  // row lse (init)
  __shared__ float ldsM[N];                  // col max (init)
  __shared__ float ldsCt[7 * CTSTRIDE + 32]; // C transposed: (c&7)*36+(c>>3)

  const int tid = threadIdx.x;
  const int cg = tid & 31;
  const int rg = tid >> 5;
  const int w = tid >> 6;
  const int r0 = rg * 8;
  const int wbase = w * TSTRIDE + cg * 9 + 4 * w;
  const long mat = blockIdx.x;

  const float4* __restrict__ src4 =
      reinterpret_cast<const float4*>(x + mat * (long)(N * N));

  // ---------- phase A: row lse -> ldsL (global pass 1, per-row temps) -----
  #pragma unroll
  for (int r = 0; r < 8; ++r) {
    float4 a = src4[(r0 + r) * 64 + cg * 2];
    float4 bq = src4[(r0 + r) * 64 + cg * 2 + 1];
    float m = fmaxf(fmaxf(fmaxf(a.x, a.y), fmaxf(a.z, a.w)),
                    fmaxf(fmaxf(bq.x, bq.y), fmaxf(bq.z, bq.w)));
    m = rmax32(m) * SCALE;
    float s = __builtin_amdgcn_exp2f(fmaf(a.x, SCALE, -m)) +
              __builtin_amdgcn_exp2f(fmaf(a.y, SCALE, -m)) +
              __builtin_amdgcn_exp2f(fmaf(a.z, SCALE, -m)) +
              __builtin_amdgcn_exp2f(fmaf(a.w, SCALE, -m)) +
              __builtin_amdgcn_exp2f(fmaf(bq.x, SCALE, -m)) +
              __builtin_amdgcn_exp2f(fmaf(bq.y, SCALE, -m)) +
              __builtin_amdgcn_exp2f(fmaf(bq.z, SCALE, -m)) +
              __builtin_amdgcn_exp2f(fmaf(bq.w, SCALE, -m));
    s = rsum32(s);
    if (cg == 0) ldsL[r0 + r] = m + __builtin_amdgcn_logf(s);
  }
  __syncthreads();

  // ---------- phase B: col max of (t - L) -> ldsM (global pass 2) ---------
  {
    float cm[8];
    #pragma unroll
    for (int k = 0; k < 8; ++k) cm[k] = -3.0e38f;
    #pragma unroll
    for (int r = 0; r < 8; ++r) {
      float Lr = ldsL[r0 + r];
      float4 a = src4[(r0 + r) * 64 + cg * 2];
      float4 bq = src4[(r0 + r) * 64 + cg * 2 + 1];
      cm[0] = fmaxf(cm[0], fmaf(a.x, SCALE, -Lr));
      cm[1] = fmaxf(cm[1], fmaf(a.y, SCALE, -Lr));
      cm[2] = fmaxf(cm[2], fmaf(a.z, SCALE, -Lr));
      cm[3] = fmaxf(cm[3], fmaf(a.w, SCALE, -Lr));
      cm[4] = fmaxf(cm[4], fmaf(bq.x, SCALE, -Lr));
      cm[5] = fmaxf(cm[5], fmaf(bq.y, SCALE, -Lr));
      cm[6] = fmaxf(cm[6], fmaf(bq.z, SCALE, -Lr));
      cm[7] = fmaxf(cm[7], fmaf(bq.w, SCALE, -Lr));
    }
    #pragma unroll
    for (int k = 0; k < 8; ++k) cm[k] = swap32_max(cm[k]);
    if (tid & 32) {
      ldsT[wbase + 4] = cm[4]; ldsT[wbase + 5] = cm[5];
      ldsT[wbase + 6] = cm[6]; ldsT[wbase + 7] = cm[7];
    } else {
      ldsT[wbase + 0] = cm[0]; ldsT[wbase + 1] = cm[1];
      ldsT[wbase + 2] = cm[2]; ldsT[wbase + 3] = cm[3];
    }
  }
  __syncthreads();
  {
    const int col = tid >> 2, q4 = tid & 3;
    const int slot = (col >> 3) * 9 + (col & 7);
    float M = -3.0e38f;
    #pragma unroll
    for (int k = 0; k < 4; ++k) {
      int row = q4 * 4 + k;
      M = fmaxf(M, ldsT[row * TSTRIDE + slot + 4 * row]);
    }
    M = fmaxf(M, dppf<0xB1>(M));
    M = fmaxf(M, dppf<0x4E>(M));
    if (q4 == 0) ldsM[col] = M;
  }
  __syncthreads();

  // -- phase C: b=2^(q-K) -> packed bf16; G_j=sum b*2^{K-L} -> C1 (pass 3) --
  unsigned bp[8][4];  // packed bf16 pairs: 32 VGPRs of matrix data
  {
    const float4* m4 = reinterpret_cast<const float4*>(ldsM);
    float4 mA = m4[cg * 2], mB = m4[cg * 2 + 1];
    float cs[8];
    #pragma unroll
    for (int k = 0; k < 8; ++k) cs[k] = 0.f;
    #pragma unroll
    for (int r = 0; r < 8; ++r) {
      float Lr = ldsL[r0 + r];
      float4 a = src4[(r0 + r) * 64 + cg * 2];
      float4 bq = src4[(r0 + r) * 64 + cg * 2 + 1];
      float q0 = fmaf(a.x, SCALE, -mA.x), q1 = fmaf(a.y, SCALE, -mA.y);
      float q2 = fmaf(a.z, SCALE, -mA.z), q3 = fmaf(a.w, SCALE, -mA.w);
      float q4v = fmaf(bq.x, SCALE, -mB.x), q5 = fmaf(bq.y, SCALE, -mB.y);
      float q6 = fmaf(bq.z, SCALE, -mB.z), q7 = fmaf(bq.w, SCALE, -mB.w);
      float Kp = fmaxf(fmaxf(fmaxf(q0, q1), fmaxf(q2, q3)),
                       fmaxf(fmaxf(q4v, q5), fmaxf(q6, q7)));
      Kp = rmax32(Kp);
      float eK = __builtin_amdgcn_exp2f(Kp - Lr);
      float e0 = __builtin_amdgcn_exp2f(q0 - Kp), e1 = __builtin_amdgcn_exp2f(q1 - Kp);
      float e2 = __builtin_amdgcn_exp2f(q2 - Kp), e3 = __builtin_amdgcn_exp2f(q3 - Kp);
      float e4 = __builtin_amdgcn_exp2f(q4v - Kp), e5 = __builtin_amdgcn_exp2f(q5 - Kp);
      float e6 = __builtin_amdgcn_exp2f(q6 - Kp), e7 = __builtin_amdgcn_exp2f(q7 - Kp);
      bp[r][0] = bfpack(e0, e1); bp[r][1] = bfpack(e2, e3);
      bp[r][2] = bfpack(e4, e5); bp[r][3] = bfpack(e6, e7);
      cs[0] = fmaf(e0, eK, cs[0]); cs[1] = fmaf(e1, eK, cs[1]);
      cs[2] = fmaf(e2, eK, cs[2]); cs[3] = fmaf(e3, eK, cs[3]);
      cs[4] = fmaf(e4, eK, cs[4]); cs[5] = fmaf(e5, eK, cs[5]);
      cs[6] = fmaf(e6, eK, cs[6]); cs[7] = fmaf(e7, eK, cs[7]);
    }
    #pragma unroll
    for (int k = 0; k < 8; ++k) cs[k] = swap32_add(cs[k]);
    if (tid & 32) {
      ldsT[wbase + 4] = cs[4]; ldsT[wbase + 5] = cs[5];
      ldsT[wbase + 6] = cs[6]; ldsT[wbase + 7] = cs[7];
    } else {
      ldsT[wbase + 0] = cs[0]; ldsT[wbase + 1] = cs[1];
      ldsT[wbase + 2] = cs[2]; ldsT[wbase + 3] = cs[3];
    }
  }
  __syncthreads();
  {
    const int col = tid >> 2, q4 = tid & 3;
    const int slot = (col >> 3) * 9 + (col & 7);
    float S = 0.f;
    #pragma unroll
    for (int k = 0; k < 4; ++k) {
      int row = q4 * 4 + k;
      S += ldsT[row * TSTRIDE + slot + 4 * row];
    }
    S += dppf<0xB1>(S);
    S += dppf<0x4E>(S);
    if (q4 == 0)
      ldsCt[(col & 7) * CTSTRIDE + (col >> 3)] =
          __builtin_amdgcn_rcpf(fmaxf(S, 1e-30f));
  }
  __syncthreads();

  // ---------- iterations 2..21 (20x): streaming low-live-set loop ----------
  float Rv[8];
  #pragma unroll 1
  for (int it = 0; it < 20; ++it) {
    // dot: stream C pairs, f32x2 accumulators (8 independent chains)
    f32x2 d2[8];
    #pragma unroll
    for (int r = 0; r < 8; ++r) d2[r] = (f32x2){0.f, 0.f};
    #pragma unroll
    for (int j = 0; j < 4; ++j) {
      f32x2 Cp;
      Cp.x = ldsCt[(2 * j) * CTSTRIDE + cg];
      Cp.y = ldsCt[(2 * j + 1) * CTSTRIDE + cg];
      #pragma unroll
      for (int r = 0; r < 8; ++r) d2[r] += bf2(bp[r][j]) * Cp;
    }
    float d[8];
    #pragma unroll
    for (int r = 0; r < 8; ++r) d[r] = d2[r].x + d2[r].y;
    // interleaved butterflies (8 independent chains)
    #pragma unroll
    for (int r = 0; r < 8; ++r) d[r] += dppf<0x121>(d[r]);
    #pragma unroll
    for (int r = 0; r < 8; ++r) d[r] += dppf<0x122>(d[r]);
    #pragma unroll
    for (int r = 0; r < 8; ++r) d[r] += dppf<0x124>(d[r]);
    #pragma unroll
    for (int r = 0; r < 8; ++r) d[r] += dppf<0x128>(d[r]);
    #pragma unroll
    for (int r = 0; r < 8; ++r) d[r] = xor16_add(d[r]);
    #pragma unroll
    for (int r = 0; r < 8; ++r)
      Rv[r] = __builtin_amdgcn_rcpf(fmaxf(d[r], 1e-30f));
    // ps per j-pair (two alternating chains), immediate combine
    float pf[8];
    #pragma unroll
    for (int j = 0; j < 4; ++j) {
      f32x2 pa = bf2(bp[0][j]) * (f32x2){Rv[0], Rv[0]};
      f32x2 pb = bf2(bp[1][j]) * (f32x2){Rv[1], Rv[1]};
      pa += bf2(bp[2][j]) * (f32x2){Rv[2], Rv[2]};
      pb += bf2(bp[3][j]) * (f32x2){Rv[3], Rv[3]};
      pa += bf2(bp[4][j]) * (f32x2){Rv[4], Rv[4]};
      pb += bf2(bp[5][j]) * (f32x2){Rv[5], Rv[5]};
      pa += bf2(bp[6][j]) * (f32x2){Rv[6], Rv[6]};
      pb += bf2(bp[7][j]) * (f32x2){Rv[7], Rv[7]};
      f32x2 ps = pa + pb;
      pf[2 * j] = ps.x;
      pf[2 * j + 1] = ps.y;
    }
    #pragma unroll
    for (int k = 0; k < 8; ++k) pf[k] = swap32_add(pf[k]);
    if (tid & 32) {
      ldsT[wbase + 4] = pf[4]; ldsT[wbase + 5] = pf[5];
      ldsT[wbase + 6] = pf[6]; ldsT[wbase + 7] = pf[7];
    } else {
      ldsT[wbase + 0] = pf[0]; ldsT[wbase + 1] = pf[1];
      ldsT[wbase + 2] = pf[2]; ldsT[wbase + 3] = pf[3];
    }
    __syncthreads();
    {
      const int col = tid >> 2, q4 = tid & 3;
      const int slot = (col >> 3) * 9 + (col & 7);
      float S = 0.f;
      #pragma unroll
      for (int k = 0; k < 4; ++k) {
        int row = q4 * 4 + k;
        S += ldsT[row * TSTRIDE + slot + 4 * row];
      }
      S += dppf<0xB1>(S);
      S += dppf<0x4E>(S);
      if (q4 == 0)
        ldsCt[(col & 7) * CTSTRIDE + (col >> 3)] =
            __builtin_amdgcn_rcpf(fmaxf(S, 1e-30f));
    }
    __syncthreads();
  }

  // ---------- output: P = b * R_i * C_j (f32) ----------
  float4* __restrict__ dst4 =
      reinterpret_cast<float4*>(out + mat * (long)(N * N));
  #pragma unroll
  for (int r = 0; r < 8; ++r) {
    f32x2 R2 = (f32x2){Rv[r], Rv[r]};
    float o[8];
    #pragma unroll
    for (int j = 0; j < 4; ++j) {
      f32x2 Cp;
      Cp.x = ldsCt[(2 * j) * CTSTRIDE + cg];
      Cp.y = ldsCt[(2 * j + 1) * CTSTRIDE + cg];
      f32x2 ov = bf2(bp[r][j]) * R2 * Cp;
      o[2 * j] = ov.x;
      o[2 * j + 1] = ov.y;
    }
    dst4[(r0 + r) * 64 + cg * 2] = make_float4(o[0], o[1], o[2], o[3]);
    dst4[(r0 + r) * 64 + cg * 2 + 1] = make_float4(o[4], o[5], o[6], o[7]);
  }
}

extern "C" void kernel_launch(void* const* d_in, const int* in_sizes, int n_in,
                              void* d_out, int out_size, void* d_ws, size_t ws_size,
                              hipStream_t stream) {
  const float* x = (const float*)d_in[0];
  float* out = (float*)d_out;
  int B = in_sizes[0] / (N * N);
  hipLaunchKernelGGL(sinkhorn_kernel, dim3(B), dim3(BLK), 0, stream, x, out);
}

// Round 17
// 127.535 us; speedup vs baseline: 5.3854x; 5.3854x over previous
//
#include <hip/hip_runtime.h>

typedef __attribute__((ext_vector_type(2))) float f32x2;
typedef unsigned int uintv2 __attribute__((ext_vector_type(2)));

#define N 256
#define BLK 1024
#define NWAVE 16
#define SCALE 144.2695040888963407f  // log2(e)/0.01
#define TSTRIDE 352                  // ≡ 0 mod 32; room for slot(<=286) + 4w(<=60)

template <int CTRL>
__device__ __forceinline__ float dppf(float v) {
  return __int_as_float(__builtin_amdgcn_update_dpp(
      0, __float_as_int(v), CTRL, 0xF, 0xF, true));
}

#if __has_builtin(__builtin_amdgcn_permlane16_swap)
__device__ __forceinline__ float xor16_add(float x) {
  uintv2 r = __builtin_amdgcn_permlane16_swap(__float_as_uint(x),
                                              __float_as_uint(x), false, false);
  return __uint_as_float(r.x) + __uint_as_float(r.y);
}
__device__ __forceinline__ float xor16_max(float x) {
  uintv2 r = __builtin_amdgcn_permlane16_swap(__float_as_uint(x),
                                              __float_as_uint(x), false, false);
  return fmaxf(__uint_as_float(r.x), __uint_as_float(r.y));
}
#else
__device__ __forceinline__ float xor16_add(float x) {
  return x + __int_as_float(__builtin_amdgcn_ds_swizzle(__float_as_int(x), 0x401F));
}
__device__ __forceinline__ float xor16_max(float x) {
  return fmaxf(x, __int_as_float(__builtin_amdgcn_ds_swizzle(__float_as_int(x), 0x401F)));
}
#endif

#if __has_builtin(__builtin_amdgcn_permlane32_swap)
__device__ __forceinline__ float swap32_add(float a) {
  uintv2 r = __builtin_amdgcn_permlane32_swap(__float_as_uint(a),
                                              __float_as_uint(a), false, false);
  return __uint_as_float(r.x) + __uint_as_float(r.y);
}
__device__ __forceinline__ float swap32_max(float a) {
  uintv2 r = __builtin_amdgcn_permlane32_swap(__float_as_uint(a),
                                              __float_as_uint(a), false, false);
  return fmaxf(__uint_as_float(r.x), __uint_as_float(r.y));
}
#else
__device__ __forceinline__ float swap32_add(float a) { return a + __shfl_xor(a, 32); }
__device__ __forceinline__ float swap32_max(float a) { return fmaxf(a, __shfl_xor(a, 32)); }
#endif

__device__ __forceinline__ float rsum32(float v) {
  v += dppf<0x121>(v);
  v += dppf<0x122>(v);
  v += dppf<0x124>(v);
  v += dppf<0x128>(v);
  return xor16_add(v);
}
__device__ __forceinline__ float rmax32(float v) {
  v = fmaxf(v, dppf<0x121>(v));
  v = fmaxf(v, dppf<0x122>(v));
  v = fmaxf(v, dppf<0x124>(v));
  v = fmaxf(v, dppf<0x128>(v));
  return xor16_max(v);
}
__device__ __forceinline__ f32x2 pkmax(f32x2 a, f32x2 b) {
  f32x2 r;
  r.x = fmaxf(a.x, b.x);
  r.y = fmaxf(a.y, b.y);
  return r;
}

// One block = one 256x256 matrix, 16 waves.
// Thread (rg=tid>>5, cg=tid&31) owns rows rg*8..+7, cols cg*8..+7.
// Dual-scaling Sinkhorn: P = b * R_i * C_j with b STATIC in f32x2 registers
// (b = 2^(u - M_j - K_i), u = t - rowlse(t), M = colmax(u), K = rowmax(u-M));
// input read from global exactly ONCE; all init phases in-register.
// Per iteration (packed math): R_i = rcp(sum_j b*C); C_j = rcp(sum_i b*R).
// LDS tree: slot = 9*(col/8)+(col&7), rotated +4*wave -> ~2-way banks only.
// launch_bounds(1024,2) is the proven allocator config (VGPR 60, zero spill);
// every attempt to force 2 blocks/CU (R3/R13/R16) spilled and lost 2-5x.
__global__ __launch_bounds__(BLK, 2)
void sinkhorn_kernel(const float* __restrict__ x, float* __restrict__ out) {
  __shared__ float ldsT[NWAVE * TSTRIDE];  // tree partials, rotated layout
  __shared__ float ldsM[N];                // col max (init)
  __shared__ float ldsCf[N];               // f32 C per col

  const int tid = threadIdx.x;
  const int cg = tid & 31;
  const int rg = tid >> 5;
  const int w = tid >> 6;
  const int r0 = rg * 8;
  const int wbase = w * TSTRIDE + cg * 9 + 4 * w;  // this lane's write base
  const long mat = blockIdx.x;

  // ---------- load once: b = x * SCALE (f32x2[8][4]) ----------
  const float4* __restrict__ src4 =
      reinterpret_cast<const float4*>(x + mat * (long)(N * N));
  f32x2 b[8][4];
  #pragma unroll
  for (int r = 0; r < 8; ++r) {
    float4 a = src4[(r0 + r) * 64 + cg * 2];
    float4 bq = src4[(r0 + r) * 64 + cg * 2 + 1];
    b[r][0] = (f32x2){a.x, a.y} * SCALE;
    b[r][1] = (f32x2){a.z, a.w} * SCALE;
    b[r][2] = (f32x2){bq.x, bq.y} * SCALE;
    b[r][3] = (f32x2){bq.z, bq.w} * SCALE;
  }

  // ---------- phase A: u = t - rowlse(t), in-register ----------
  #pragma unroll
  for (int r = 0; r < 8; ++r) {
    f32x2 m2 = pkmax(pkmax(b[r][0], b[r][1]), pkmax(b[r][2], b[r][3]));
    float m = rmax32(fmaxf(m2.x, m2.y));
    float s = 0.f;
    #pragma unroll
    for (int j = 0; j < 4; ++j) {
      s += __builtin_amdgcn_exp2f(b[r][j].x - m);
      s += __builtin_amdgcn_exp2f(b[r][j].y - m);
    }
    s = rsum32(s);
    float L = m + __builtin_amdgcn_logf(s);  // v_log_f32 = log2
    #pragma unroll
    for (int j = 0; j < 4; ++j) b[r][j] -= (f32x2){L, L};
  }

  // ---------- phase B: M_j = colmax(u) via tree ----------
  {
    f32x2 cm[4];
    #pragma unroll
    for (int j = 0; j < 4; ++j) cm[j] = b[0][j];
    #pragma unroll
    for (int r = 1; r < 8; ++r)
      #pragma unroll
      for (int j = 0; j < 4; ++j) cm[j] = pkmax(cm[j], b[r][j]);
    float cmf[8] = {cm[0].x, cm[0].y, cm[1].x, cm[1].y,
                    cm[2].x, cm[2].y, cm[3].x, cm[3].y};
    #pragma unroll
    for (int k = 0; k < 8; ++k) cmf[k] = swap32_max(cmf[k]);
    if (tid & 32) {
      ldsT[wbase + 4] = cmf[4]; ldsT[wbase + 5] = cmf[5];
      ldsT[wbase + 6] = cmf[6]; ldsT[wbase + 7] = cmf[7];
    } else {
      ldsT[wbase + 0] = cmf[0]; ldsT[wbase + 1] = cmf[1];
      ldsT[wbase + 2] = cmf[2]; ldsT[wbase + 3] = cmf[3];
    }
  }
  __syncthreads();
  {
    const int col = tid >> 2, q4 = tid & 3;
    const int slot = (col >> 3) * 9 + (col & 7);
    float M = -3.0e38f;
    #pragma unroll
    for (int k = 0; k < 4; ++k) {
      int row = q4 * 4 + k;
      M = fmaxf(M, ldsT[row * TSTRIDE + slot + 4 * row]);
    }
    M = fmaxf(M, dppf<0xB1>(M));
    M = fmaxf(M, dppf<0x4E>(M));
    if (q4 == 0) ldsM[col] = M;
  }
  __syncthreads();

  // ---------- phase C: b = 2^(u-M-K); G_j = sum_i b*2^{K_i} -> C1 ----------
  {
    const float4* m4 = reinterpret_cast<const float4*>(ldsM);
    float4 mA = m4[cg * 2], mB = m4[cg * 2 + 1];
    f32x2 Mv[4] = {{mA.x, mA.y}, {mA.z, mA.w}, {mB.x, mB.y}, {mB.z, mB.w}};
    f32x2 cs[4];
    cs[0] = cs[1] = cs[2] = cs[3] = (f32x2){0.f, 0.f};
    #pragma unroll
    for (int r = 0; r < 8; ++r) {
      f32x2 v0 = b[r][0] - Mv[0], v1 = b[r][1] - Mv[1];
      f32x2 v2 = b[r][2] - Mv[2], v3 = b[r][3] - Mv[3];
      f32x2 km = pkmax(pkmax(v0, v1), pkmax(v2, v3));
      float K = rmax32(fmaxf(km.x, km.y));  // row max of (u - M), <= 0
      float eK = __builtin_amdgcn_exp2f(K);
      b[r][0].x = __builtin_amdgcn_exp2f(v0.x - K);
      b[r][0].y = __builtin_amdgcn_exp2f(v0.y - K);
      b[r][1].x = __builtin_amdgcn_exp2f(v1.x - K);
      b[r][1].y = __builtin_amdgcn_exp2f(v1.y - K);
      b[r][2].x = __builtin_amdgcn_exp2f(v2.x - K);
      b[r][2].y = __builtin_amdgcn_exp2f(v2.y - K);
      b[r][3].x = __builtin_amdgcn_exp2f(v3.x - K);
      b[r][3].y = __builtin_amdgcn_exp2f(v3.y - K);
      f32x2 eK2 = (f32x2){eK, eK};
      cs[0] += b[r][0] * eK2;
      cs[1] += b[r][1] * eK2;
      cs[2] += b[r][2] * eK2;
      cs[3] += b[r][3] * eK2;
    }
    float csf[8] = {cs[0].x, cs[0].y, cs[1].x, cs[1].y,
                    cs[2].x, cs[2].y, cs[3].x, cs[3].y};
    #pragma unroll
    for (int k = 0; k < 8; ++k) csf[k] = swap32_add(csf[k]);
    if (tid & 32) {
      ldsT[wbase + 4] = csf[4]; ldsT[wbase + 5] = csf[5];
      ldsT[wbase + 6] = csf[6]; ldsT[wbase + 7] = csf[7];
    } else {
      ldsT[wbase + 0] = csf[0]; ldsT[wbase + 1] = csf[1];
      ldsT[wbase + 2] = csf[2]; ldsT[wbase + 3] = csf[3];
    }
  }
  __syncthreads();
  {
    const int col = tid >> 2, q4 = tid & 3;
    const int slot = (col >> 3) * 9 + (col & 7);
    float S = 0.f;
    #pragma unroll
    for (int k = 0; k < 4; ++k) {
      int row = q4 * 4 + k;
      S += ldsT[row * TSTRIDE + slot + 4 * row];
    }
    S += dppf<0xB1>(S);
    S += dppf<0x4E>(S);
    if (q4 == 0) ldsCf[col] = __builtin_amdgcn_rcpf(fmaxf(S, 1e-30f));
  }
  __syncthreads();

  f32x2 Cv[4];
  {
    const float4* cf4 = reinterpret_cast<const float4*>(ldsCf);
    float4 cA = cf4[cg * 2], cB = cf4[cg * 2 + 1];
    Cv[0] = (f32x2){cA.x, cA.y}; Cv[1] = (f32x2){cA.z, cA.w};
    Cv[2] = (f32x2){cB.x, cB.y}; Cv[3] = (f32x2){cB.z, cB.w};
  }

  // ---------- iterations 2..20 (19x): packed-math R then C ----------
  #pragma unroll 1
  for (int it = 0; it < 19; ++it) {
    f32x2 ps[4];
    ps[0] = ps[1] = ps[2] = ps[3] = (f32x2){0.f, 0.f};
    #pragma unroll
    for (int r = 0; r < 8; ++r) {
      f32x2 s2 = b[r][0] * Cv[0];
      s2 += b[r][1] * Cv[1];
      s2 += b[r][2] * Cv[2];
      s2 += b[r][3] * Cv[3];
      float s = rsum32(s2.x + s2.y);
      float Rr = __builtin_amdgcn_rcpf(fmaxf(s, 1e-30f));
      f32x2 R2 = (f32x2){Rr, Rr};
      ps[0] += b[r][0] * R2;
      ps[1] += b[r][1] * R2;
      ps[2] += b[r][2] * R2;
      ps[3] += b[r][3] * R2;
    }
    float pf[8] = {ps[0].x, ps[0].y, ps[1].x, ps[1].y,
                   ps[2].x, ps[2].y, ps[3].x, ps[3].y};
    #pragma unroll
    for (int k = 0; k < 8; ++k) pf[k] = swap32_add(pf[k]);
    if (tid & 32) {
      ldsT[wbase + 4] = pf[4]; ldsT[wbase + 5] = pf[5];
      ldsT[wbase + 6] = pf[6]; ldsT[wbase + 7] = pf[7];
    } else {
      ldsT[wbase + 0] = pf[0]; ldsT[wbase + 1] = pf[1];
      ldsT[wbase + 2] = pf[2]; ldsT[wbase + 3] = pf[3];
    }
    __syncthreads();
    {
      const int col = tid >> 2, q4 = tid & 3;
      const int slot = (col >> 3) * 9 + (col & 7);
      float S = 0.f;
      #pragma unroll
      for (int k = 0; k < 4; ++k) {
        int row = q4 * 4 + k;
        S += ldsT[row * TSTRIDE + slot + 4 * row];
      }
      S += dppf<0xB1>(S);
      S += dppf<0x4E>(S);
      if (q4 == 0) ldsCf[col] = __builtin_amdgcn_rcpf(fmaxf(S, 1e-30f));
    }
    __syncthreads();
    {
      const float4* cf4 = reinterpret_cast<const float4*>(ldsCf);
      float4 cA = cf4[cg * 2], cB = cf4[cg * 2 + 1];
      Cv[0] = (f32x2){cA.x, cA.y}; Cv[1] = (f32x2){cA.z, cA.w};
      Cv[2] = (f32x2){cB.x, cB.y}; Cv[3] = (f32x2){cB.z, cB.w};
    }
  }

  // ---------- peeled iteration 21: keep R, final C ----------
  float R[8];
  {
    f32x2 ps[4];
    ps[0] = ps[1] = ps[2] = ps[3] = (f32x2){0.f, 0.f};
    #pragma unroll
    for (int r = 0; r < 8; ++r) {
      f32x2 s2 = b[r][0] * Cv[0];
      s2 += b[r][1] * Cv[1];
      s2 += b[r][2] * Cv[2];
      s2 += b[r][3] * Cv[3];
      float s = rsum32(s2.x + s2.y);
      float Rr = __builtin_amdgcn_rcpf(fmaxf(s, 1e-30f));
      R[r] = Rr;
      f32x2 R2 = (f32x2){Rr, Rr};
      ps[0] += b[r][0] * R2;
      ps[1] += b[r][1] * R2;
      ps[2] += b[r][2] * R2;
      ps[3] += b[r][3] * R2;
    }
    float pf[8] = {ps[0].x, ps[0].y, ps[1].x, ps[1].y,
                   ps[2].x, ps[2].y, ps[3].x, ps[3].y};
    #pragma unroll
    for (int k = 0; k < 8; ++k) pf[k] = swap32_add(pf[k]);
    if (tid & 32) {
      ldsT[wbase + 4] = pf[4]; ldsT[wbase + 5] = pf[5];
      ldsT[wbase + 6] = pf[6]; ldsT[wbase + 7] = pf[7];
    } else {
      ldsT[wbase + 0] = pf[0]; ldsT[wbase + 1] = pf[1];
      ldsT[wbase + 2] = pf[2]; ldsT[wbase + 3] = pf[3];
    }
    __syncthreads();
    {
      const int col = tid >> 2, q4 = tid & 3;
      const int slot = (col >> 3) * 9 + (col & 7);
      float S = 0.f;
      #pragma unroll
      for (int k = 0; k < 4; ++k) {
        int row = q4 * 4 + k;
        S += ldsT[row * TSTRIDE + slot + 4 * row];
      }
      S += dppf<0xB1>(S);
      S += dppf<0x4E>(S);
      if (q4 == 0) ldsCf[col] = __builtin_amdgcn_rcpf(fmaxf(S, 1e-30f));
    }
    __syncthreads();
  }

  // ---------- output: P = b * R_i * C_j ----------
  const float4* cf4 = reinterpret_cast<const float4*>(ldsCf);
  float4 cA = cf4[cg * 2], cB = cf4[cg * 2 + 1];
  f32x2 C0 = (f32x2){cA.x, cA.y}, C1 = (f32x2){cA.z, cA.w};
  f32x2 C2 = (f32x2){cB.x, cB.y}, C3 = (f32x2){cB.z, cB.w};
  float4* __restrict__ dst4 =
      reinterpret_cast<float4*>(out + mat * (long)(N * N));
  #pragma unroll
  for (int r = 0; r < 8; ++r) {
    f32x2 R2 = (f32x2){R[r], R[r]};
    f32x2 o0 = b[r][0] * R2 * C0;
    f32x2 o1 = b[r][1] * R2 * C1;
    f32x2 o2 = b[r][2] * R2 * C2;
    f32x2 o3 = b[r][3] * R2 * C3;
    dst4[(r0 + r) * 64 + cg * 2] = make_float4(o0.x, o0.y, o1.x, o1.y);
    dst4[(r0 + r) * 64 + cg * 2 + 1] = make_float4(o2.x, o2.y, o3.x, o3.y);
  }
}

extern "C" void kernel_launch(void* const* d_in, const int* in_sizes, int n_in,
                              void* d_out, int out_size, void* d_ws, size_t ws_size,
                              hipStream_t stream) {
  const float* x = (const float*)d_in[0];
  float* out = (float*)d_out;
  int B = in_sizes[0] / (N * N);
  hipLaunchKernelGGL(sinkhorn_kernel, dim3(B), dim3(BLK), 0, stream, x, out);
}